// Round 16
// baseline (408.736 us; speedup 1.0000x reference)
//
#include <hip/hip_runtime.h>

#define T_ 10
#define B_ 4
#define N_ 2048
#define NTOT 8192
#define F_ 64
#define H_ 128
#define NHEADS 4
#define D_ 32
#define E_ 65536
#define EF 73728          // E + NTOT self-loops
#define HPAD 136

typedef __bf16 bf16x8 __attribute__((ext_vector_type(8)));
typedef float f32x4 __attribute__((ext_vector_type(4)));
typedef unsigned short u16;

#define GLD_LDS16(g, l) __builtin_amdgcn_global_load_lds( \
    (const __attribute__((address_space(1))) unsigned int*)(g), \
    (__attribute__((address_space(3))) unsigned int*)(l), 16, 0, 0)
// wait until at most N vector-memory ops outstanding (expcnt=7, lgkmcnt=15 -> not waited)
#define WAITVM(N) __builtin_amdgcn_s_waitcnt(0xF70 | (N))

__device__ __forceinline__ float bf2f(u16 u){
  union { unsigned int i; float f; } v; v.i = ((unsigned int)u) << 16; return v.f;
}
__device__ __forceinline__ u16 f2bf(float f){
  union { float f; unsigned int i; } v; v.f = f;
  return (u16)((v.i + 0x7FFFu + ((v.i >> 16) & 1u)) >> 16);
}
__device__ __forceinline__ float sigf(float x){ return 1.f / (1.f + __expf(-x)); }
__device__ __forceinline__ float tanhfast(float x){ return 1.f - 2.f / (__expf(2.f * x) + 1.f); }
__device__ __forceinline__ float lrelu(float x){ return x > 0.f ? x : 0.2f * x; }

// ---------------- CSR build ----------------
__global__ __launch_bounds__(256) void k_init(int* __restrict__ cnt){
  int i = blockIdx.x * 256 + threadIdx.x;
  if(i < NTOT) cnt[i] = 0;
}

__global__ __launch_bounds__(256) void k_count(const int* __restrict__ ei, int* __restrict__ cnt){
  int e = blockIdx.x * 256 + threadIdx.x;
  if(e < E_) atomicAdd(&cnt[ei[E_ + e]], 1);
}

__global__ __launch_bounds__(1024) void k_scan(const int* __restrict__ cnt,
                                               int* __restrict__ rowst,
                                               int* __restrict__ cursor){
  __shared__ int lds[1024];
  const int t = threadIdx.x;
  int loc[8];
  int s = 0;
  #pragma unroll
  for(int i = 0; i < 8; i++){ loc[i] = s; s += cnt[t * 8 + i]; }
  lds[t] = s;
  __syncthreads();
  for(int off = 1; off < 1024; off <<= 1){
    int v = lds[t];
    int a = (t >= off) ? lds[t - off] : 0;
    __syncthreads();
    lds[t] = v + a;
    __syncthreads();
  }
  const int base = (t > 0) ? lds[t - 1] : 0;
  #pragma unroll
  for(int i = 0; i < 8; i++){
    rowst[t * 8 + i] = base + loc[i];
    cursor[t * 8 + i] = 0;
  }
  if(t == 1023) rowst[NTOT] = lds[1023];
}

__global__ __launch_bounds__(256) void k_fill(const int* __restrict__ ei,
                                              const int* __restrict__ rowst,
                                              int* __restrict__ cursor,
                                              int* __restrict__ csr,
                                              int* __restrict__ csr_dst){
  int e = blockIdx.x * 256 + threadIdx.x;
  if(e < E_){
    int d = ei[E_ + e];
    int pos = atomicAdd(&cursor[d], 1);
    csr[rowst[d] + pos] = ei[e];
    csr_dst[rowst[d] + pos] = d;
  }
}

// ---- weight conversions: y=0..3 gate-permuted LSTM mats; y=4 GAT W^T ----
__global__ __launch_bounds__(256) void k_wconv(const float* __restrict__ s0, u16* __restrict__ d0,
                                               const float* __restrict__ s1, u16* __restrict__ d1,
                                               const float* __restrict__ s2, u16* __restrict__ d2,
                                               const float* __restrict__ s3, u16* __restrict__ d3,
                                               const float* __restrict__ W, u16* __restrict__ Wt){
  int i = blockIdx.x * 256 + threadIdx.x;
  if(blockIdx.y == 4){
    if(i < H_ * F_){
      int nn = i >> 6, f = i & 63;
      Wt[i] = f2bf(W[f * H_ + nn]);
    }
    return;
  }
  const float* src = blockIdx.y == 0 ? s0 : blockIdx.y == 1 ? s1 : blockIdx.y == 2 ? s2 : s3;
  u16* dst = blockIdx.y == 0 ? d0 : blockIdx.y == 1 ? d1 : blockIdx.y == 2 ? d2 : d3;
  if(i < 512 * 128){
    int p = i >> 7, k = i & 127;
    int w = p >> 6, g = (p >> 4) & 3, l = p & 15;
    int row = g * 128 + w * 16 + l;
    dst[i] = f2bf(src[row * 128 + k]);
  }
}

// ---------------- MFMA GAT projection + attention coefficients ----------------
__global__ __launch_bounds__(256) void k_projm(const float* __restrict__ x,
    const u16* __restrict__ Wt, const float* __restrict__ att_s, const float* __restrict__ att_d,
    u16* __restrict__ hbuf, float* __restrict__ asrc, float* __restrict__ adst){
  const int tid  = threadIdx.x;
  const int wave = tid >> 6;
  const int lane = tid & 63;
  const int l15  = lane & 15;
  const int quad = lane >> 4;
  const int r0   = blockIdx.x * 64 + wave * 16;
  const int row  = r0 + l15;
  const int t = row >> 13, nt = row & 8191;
  const int b = nt >> 11, n = nt & 2047;
  const float* xrow = x + (((size_t)b * T_ + t) * N_ + n) * F_;

  bf16x8 a[2];
  #pragma unroll
  for(int ks = 0; ks < 2; ks++){
    const float4 f0 = *(const float4*)(xrow + ks * 32 + quad * 8);
    const float4 f1 = *(const float4*)(xrow + ks * 32 + quad * 8 + 4);
    bf16x8 av;
    av[0] = (__bf16)f0.x; av[1] = (__bf16)f0.y; av[2] = (__bf16)f0.z; av[3] = (__bf16)f0.w;
    av[4] = (__bf16)f1.x; av[5] = (__bf16)f1.y; av[6] = (__bf16)f1.z; av[7] = (__bf16)f1.w;
    a[ks] = av;
  }

  f32x4 acc[8];
  #pragma unroll
  for(int c = 0; c < 8; c++){ f32x4 z = {0.f,0.f,0.f,0.f}; acc[c] = z; }
  #pragma unroll
  for(int c = 0; c < 8; c++){
    #pragma unroll
    for(int ks = 0; ks < 2; ks++){
      const bf16x8 bv = *(const bf16x8*)(Wt + (c * 16 + l15) * F_ + ks * 32 + quad * 8);
      acc[c] = __builtin_amdgcn_mfma_f32_16x16x32_bf16(a[ks], bv, acc[c], 0, 0, 0);
    }
  }

  float ps[4][4], pd[4][4];   // [r][head]
  #pragma unroll
  for(int r = 0; r < 4; r++)
    #pragma unroll
    for(int h = 0; h < 4; h++){ ps[r][h] = 0.f; pd[r][h] = 0.f; }

  #pragma unroll
  for(int c = 0; c < 8; c++){
    const int col = c * 16 + l15;
    const float asv = att_s[col];
    const float adv = att_d[col];
    const int head = c >> 1;
    #pragma unroll
    for(int r = 0; r < 4; r++){
      const float v = acc[c][r];
      hbuf[(size_t)(r0 + quad * 4 + r) * H_ + col] = f2bf(v);
      ps[r][head] += v * asv;
      pd[r][head] += v * adv;
    }
  }
  #pragma unroll
  for(int m = 8; m >= 1; m >>= 1){
    #pragma unroll
    for(int r = 0; r < 4; r++)
      #pragma unroll
      for(int h = 0; h < 4; h++){
        ps[r][h] += __shfl_xor(ps[r][h], m);
        pd[r][h] += __shfl_xor(pd[r][h], m);
      }
  }
  if(l15 == 0){
    #pragma unroll
    for(int r = 0; r < 4; r++){
      const int rw = r0 + quad * 4 + r;
      #pragma unroll
      for(int h = 0; h < 4; h++){
        asrc[(size_t)rw * NHEADS + h] = ps[r][h];
        adst[(size_t)rw * NHEADS + h] = pd[r][h];
      }
    }
  }
}

// ---------------- GAT P1: per-(t,node,head) softmax max+denominator ----------------
__global__ __launch_bounds__(256) void k_mden(const float* __restrict__ asrc,
    const float* __restrict__ adst, const int* __restrict__ rowst, const int* __restrict__ csr,
    float* __restrict__ m_, float* __restrict__ den_){
  const int gid = blockIdx.x * 256 + threadIdx.x;   // (t,node,head), head fastest
  const int head = gid & 3;
  const int node = (gid >> 2) & 8191;
  const int t = gid >> 15;
  const int rbase = t * NTOT;
  const float ad = adst[(size_t)(rbase + node) * NHEADS + head];
  float m = lrelu(asrc[(size_t)(rbase + node) * NHEADS + head] + ad);  // self-loop
  float den = 1.f;
  const int rs = rowst[node], re = rowst[node + 1];
  for(int i = rs; i < re; i++){
    const int s = csr[i];
    const float ev = lrelu(asrc[(size_t)(rbase + s) * NHEADS + head] + ad);
    const float nm = fmaxf(m, ev);
    den = den * __expf(m - nm) + __expf(ev - nm);
    m = nm;
  }
  m_[gid] = m;
  den_[gid] = den;
}

// ---------------- GAT P2: per-(t,csrpos) alpha for all 4 heads ----------------
__global__ __launch_bounds__(256) void k_alpha(const float* __restrict__ asrc,
    const float* __restrict__ adst, const int* __restrict__ csr, const int* __restrict__ csr_dst,
    const float* __restrict__ m_, const float* __restrict__ den_, float* __restrict__ alphaC){
  const int p = blockIdx.x * 256 + threadIdx.x;   // 0..EF-1
  const int t = blockIdx.y;
  const int rbase = t * NTOT;
  int s, d;
  if(p < E_){ s = csr[p]; d = csr_dst[p]; } else { s = d = p - E_; }
  const float4 as4 = *(const float4*)&asrc[(size_t)(rbase + s) * NHEADS];
  const float4 ad4 = *(const float4*)&adst[(size_t)(rbase + d) * NHEADS];
  const float4 m4  = *(const float4*)&m_[(size_t)(rbase + d) * NHEADS];
  const float4 dn4 = *(const float4*)&den_[(size_t)(rbase + d) * NHEADS];
  float4 o;
  o.x = __expf(lrelu(as4.x + ad4.x) - m4.x) / dn4.x;
  o.y = __expf(lrelu(as4.y + ad4.y) - m4.y) / dn4.y;
  o.z = __expf(lrelu(as4.z + ad4.z) - m4.z) / dn4.z;
  o.w = __expf(lrelu(as4.w + ad4.w) - m4.w) / dn4.w;
  *(float4*)&alphaC[((size_t)t * EF + p) * NHEADS] = o;
}

// ---------------- GAT P3: aggregation; wave per (t,node), lane covers dims (lane, lane+64) ----------------
__global__ __launch_bounds__(256) void k_agg(const u16* __restrict__ hbuf,
    const float* __restrict__ alphaC, const int* __restrict__ rowst, const int* __restrict__ csr,
    const float* __restrict__ gbias, u16* __restrict__ spat){
  const int tid = threadIdx.x;
  const int wave = tid >> 6;
  const int lane = tid & 63;
  const int task = blockIdx.x * 4 + wave;
  const int node = task & 8191;
  const int t = task >> 13;
  const int rbase = t * NTOT;
  const int d0 = lane, d1 = lane + 64;

  const float4 aself = *(const float4*)&alphaC[((size_t)t * EF + E_ + node) * NHEADS];
  float acc0 = (lane < 32 ? aself.x : aself.y) * bf2f(hbuf[(size_t)(rbase + node) * H_ + d0]);
  float acc1 = (lane < 32 ? aself.z : aself.w) * bf2f(hbuf[(size_t)(rbase + node) * H_ + d1]);
  const int rs = rowst[node], re = rowst[node + 1];
  for(int i = rs; i < re; i++){
    const int s = csr[i];
    const float4 av = *(const float4*)&alphaC[((size_t)t * EF + i) * NHEADS];
    const float a0 = lane < 32 ? av.x : av.y;
    const float a1 = lane < 32 ? av.z : av.w;
    acc0 += a0 * bf2f(hbuf[(size_t)(rbase + s) * H_ + d0]);
    acc1 += a1 * bf2f(hbuf[(size_t)(rbase + s) * H_ + d1]);
  }
  const float v0 = acc0 + gbias[d0];
  const float v1 = acc1 + gbias[d1];
  spat[(size_t)(rbase + node) * H_ + d0] = f2bf(v0 > 0.f ? v0 : 0.f);
  spat[(size_t)(rbase + node) * H_ + d1] = f2bf(v1 > 0.f ? v1 : 0.f);
}

// ---------------- 2-layer LSTM: DMA weight staging + explicit vmcnt + fused LayerNorm ----------
// global_load_lds width=16 streams weights HBM/L2 -> LDS (no ds_writes, no staging VGPRs).
// FRAGMENT-ORDERED layout: lane i's DMA chunk IS lane i's B-fragment -> ds_read at lane*16,
// conflict-free. Wave-private 3-buffer ring, depth-2 prefetch, correctness via explicit
// s_waitcnt vmcnt(8/4/0) per phase (the DMA has no dest register; without this the reads race).
__global__ __launch_bounds__(512) __attribute__((amdgpu_waves_per_eu(2))) void k_lstm(
    const u16* __restrict__ spat,
    const u16* __restrict__ Wp_ih0, const u16* __restrict__ Wp_hh0,
    const float* __restrict__ bih0, const float* __restrict__ bhh0,
    const u16* __restrict__ Wp_ih1, const u16* __restrict__ Wp_hh1,
    const float* __restrict__ bih1, const float* __restrict__ bhh1,
    const float* __restrict__ lng, const float* __restrict__ lnb,
    float* __restrict__ out)
{
  __shared__ __align__(16) unsigned char wbuf[8][3][4096];   // 96 KB DMA ring
  __shared__ __align__(16) u16 xin[32 * HPAD];               // 8.5 KB
  __shared__ __align__(16) u16 h0s[2][32 * HPAD];            // 17 KB
  __shared__ __align__(16) u16 h1s[2][32 * HPAD];            // 17 KB
  __shared__ __align__(16) float hfin[32 * 129];             // 16.5 KB fp32 final h1

  const int tid  = threadIdx.x;
  const int wave = tid >> 6;
  const int lane = tid & 63;
  const int l15  = lane & 15;
  const int quad = lane >> 4;
  const int n0   = blockIdx.x * 32;
  const int dim  = wave * 16 + l15;

  for(int i = tid; i < 2 * 32 * HPAD; i += 512){
    ((u16*)h0s)[i] = 0; ((u16*)h1s)[i] = 0;
  }
  // xin(t=0): 32 rows x 16 chunks of 16B = 512 chunks
  {
    const u16* src = spat + (size_t)n0 * H_;
    const int r = tid >> 4, c = tid & 15;
    *(uint4*)(xin + r * HPAD + c * 8) = *(const uint4*)(src + r * 128 + c * 8);
  }
  float cst[16];
  #pragma unroll
  for(int i = 0; i < 16; i++) cst[i] = 0.f;

  float bias[2][4];
  #pragma unroll
  for(int g = 0; g < 4; g++){
    bias[0][g] = bih0[g * 128 + dim] + bhh0[g * 128 + dim];
    bias[1][g] = bih1[g * 128 + dim] + bhh1[g * 128 + dim];
  }
  __syncthreads();

  // DMA one K=32 slice of matrix M into ring buf r, fragment-ordered:
  // instr j (=nt tile): lane i sources row (wave*64 + j*16 + (i&15)), bytes (i>>4)*16 of the
  // 64B k-slice; HW lands it at dest + i*16 => read back at nt*1024 + lane*16 (lane-linear).
  auto stage = [&](const u16* M, int ks, int r){
    #pragma unroll
    for(int j = 0; j < 4; j++){
      const u16* g = M + (size_t)(wave * 64 + j * 16 + l15) * 128 + ks * 32 + quad * 8;
      GLD_LDS16(g, &wbuf[wave][r][j * 1024]);
    }
  };

  #pragma unroll 1
  for(int t = 0; t < T_; t++){
    const int rp = t & 1, wp = rp ^ 1;
    #pragma unroll
    for(int layer = 0; layer < 2; layer++){
      const u16* Wih = layer ? Wp_ih1 : Wp_ih0;
      const u16* Whh = layer ? Wp_hh1 : Wp_hh0;
      const u16* xp  = layer ? h0s[wp] : xin;      // a-input, phases 0-3
      const u16* hp  = layer ? h1s[rp] : h0s[rp];  // a-input, phases 4-7

      f32x4 acc[2][4];
      #pragma unroll
      for(int nt = 0; nt < 4; nt++){
        const float bv = bias[layer][nt];
        f32x4 b4 = {bv, bv, bv, bv};
        acc[0][nt] = b4; acc[1][nt] = b4;
      }

      stage(Wih, 0, 0);
      stage(Wih, 1, 1);
      #pragma unroll
      for(int p = 0; p < 8; p++){
        if(p < 6){                          // depth-2 prefetch: slice p+2
          const int q = p + 2;
          stage((q < 4) ? Wih : Whh, q & 3, q % 3);
        }
        // slice p must be complete; slices p+1 (4 DMAs) and p+2 (4 DMAs) may stay in flight
        if(p < 6)      WAITVM(8);
        else if(p == 6) WAITVM(4);
        else            WAITVM(0);

        const u16* ap = (p < 4) ? xp : hp;
        const int ka = (p & 3) * 32 + quad * 8;
        const bf16x8 a0 = *(const bf16x8*)(ap + l15 * HPAD + ka);
        const bf16x8 a1 = *(const bf16x8*)(ap + (16 + l15) * HPAD + ka);
        const unsigned char* rb = &wbuf[wave][p % 3][0];
        #pragma unroll
        for(int nt = 0; nt < 4; nt++){
          const bf16x8 b = *(const bf16x8*)(rb + nt * 1024 + lane * 16);
          acc[0][nt] = __builtin_amdgcn_mfma_f32_16x16x32_bf16(a0, b, acc[0][nt], 0, 0, 0);
          acc[1][nt] = __builtin_amdgcn_mfma_f32_16x16x32_bf16(a1, b, acc[1][nt], 0, 0, 0);
        }
      }

      // in-register epilogue: C/D row = quad*4 + r (node), this lane's dim fixed
      u16* hcur = layer ? h1s[wp] : h0s[wp];
      #pragma unroll
      for(int mt = 0; mt < 2; mt++){
        #pragma unroll
        for(int r = 0; r < 4; r++){
          const int node = mt * 16 + quad * 4 + r;
          const float gi = acc[mt][0][r];
          const float gf = acc[mt][1][r];
          const float gg = acc[mt][2][r];
          const float go = acc[mt][3][r];
          const int ci = layer * 8 + mt * 4 + r;
          const float c = sigf(gf) * cst[ci] + sigf(gi) * tanhfast(gg);
          cst[ci] = c;
          const float hv = sigf(go) * tanhfast(c);
          hcur[node * HPAD + dim] = f2bf(hv);
          if(layer == 1 && t == T_ - 1)
            hfin[node * 129 + dim] = hv;
        }
      }
      // after layer 1: copy next timestep's x-tile (barrier below covers it)
      if(layer == 1 && t < T_ - 1){
        const u16* src = spat + (size_t)((t + 1) * NTOT + n0) * H_;
        const int r = tid >> 4, c = tid & 15;
        *(uint4*)(xin + r * HPAD + c * 8) = *(const uint4*)(src + r * 128 + c * 8);
      }
      __syncthreads();
    }
  }

  // ---- fused LayerNorm: 16 threads per node, 8 dims each, fp32 from hfin ----
  {
    const int node = tid >> 4;
    const int c0 = (tid & 15) * 8;
    float v[8];
    #pragma unroll
    for(int j = 0; j < 8; j++) v[j] = hfin[node * 129 + c0 + j];
    float s = 0.f;
    #pragma unroll
    for(int j = 0; j < 8; j++) s += v[j];
    #pragma unroll
    for(int m = 8; m >= 1; m >>= 1) s += __shfl_xor(s, m);
    const float mu = s * (1.f / H_);
    float q = 0.f;
    #pragma unroll
    for(int j = 0; j < 8; j++){ const float d = v[j] - mu; q += d * d; }
    #pragma unroll
    for(int m = 8; m >= 1; m >>= 1) q += __shfl_xor(q, m);
    const float rstd = rsqrtf(q * (1.f / H_) + 1e-5f);
    #pragma unroll
    for(int j = 0; j < 8; j++)
      out[(size_t)(n0 + node) * H_ + c0 + j] = (v[j] - mu) * rstd * lng[c0 + j] + lnb[c0 + j];
  }
}

extern "C" void kernel_launch(void* const* d_in, const int* in_sizes, int n_in,
                              void* d_out, int out_size, void* d_ws, size_t ws_size,
                              hipStream_t stream) {
  (void)in_sizes; (void)n_in; (void)out_size; (void)ws_size;
  const float* x     = (const float*)d_in[0];
  const float* W     = (const float*)d_in[1];
  const float* att_s = (const float*)d_in[2];
  const float* att_d = (const float*)d_in[3];
  const float* gbias = (const float*)d_in[4];
  const float* Wih0  = (const float*)d_in[5];
  const float* Whh0  = (const float*)d_in[6];
  const float* bih0  = (const float*)d_in[7];
  const float* bhh0  = (const float*)d_in[8];
  const float* Wih1  = (const float*)d_in[9];
  const float* Whh1  = (const float*)d_in[10];
  const float* bih1  = (const float*)d_in[11];
  const float* bhh1  = (const float*)d_in[12];
  const float* lng   = (const float*)d_in[13];
  const float* lnb   = (const float*)d_in[14];
  const int*   ei    = (const int*)d_in[15];
  float* out = (float*)d_out;

  char* p = (char*)d_ws;
  auto carve = [&](size_t bytes) -> void* {
    void* r = (void*)p;
    p += (bytes + 255) & ~(size_t)255;
    return r;
  };
  u16* Wp_ih0 = (u16*)carve(512 * 128 * 2);
  u16* Wp_hh0 = (u16*)carve(512 * 128 * 2);
  u16* Wp_ih1 = (u16*)carve(512 * 128 * 2);
  u16* Wp_hh1 = (u16*)carve(512 * 128 * 2);
  u16* Wt     = (u16*)carve(H_ * F_ * 2);
  u16*   hbuf   = (u16*)carve((size_t)T_ * NTOT * H_ * 2);           // 21 MB bf16
  float* asrc   = (float*)carve((size_t)T_ * NTOT * NHEADS * 4);
  float* adst   = (float*)carve((size_t)T_ * NTOT * NHEADS * 4);
  float* m_     = (float*)carve((size_t)T_ * NTOT * NHEADS * 4);
  float* den_   = (float*)carve((size_t)T_ * NTOT * NHEADS * 4);
  float* alphaC = (float*)carve((size_t)T_ * EF * NHEADS * 4);       // 11.8 MB
  u16*   spat   = (u16*)carve((size_t)T_ * NTOT * H_ * 2);           // 21 MB bf16
  int*   cnt    = (int*)carve(NTOT * 4);
  int*   curs   = (int*)carve(NTOT * 4);
  int*   rowst  = (int*)carve((NTOT + 1) * 4);
  int*   csr    = (int*)carve((size_t)E_ * 4);
  int*   csrd   = (int*)carve((size_t)E_ * 4);

  hipLaunchKernelGGL(k_init,  dim3(32),        dim3(256),  0, stream, cnt);
  hipLaunchKernelGGL(k_count, dim3(256),       dim3(256),  0, stream, ei, cnt);
  hipLaunchKernelGGL(k_scan,  dim3(1),         dim3(1024), 0, stream, cnt, rowst, curs);
  hipLaunchKernelGGL(k_fill,  dim3(256),       dim3(256),  0, stream, ei, rowst, curs, csr, csrd);
  hipLaunchKernelGGL(k_wconv, dim3(256, 5),    dim3(256),  0, stream,
                     Wih0, Wp_ih0, Whh0, Wp_hh0, Wih1, Wp_ih1, Whh1, Wp_hh1, W, Wt);
  hipLaunchKernelGGL(k_projm, dim3(1280),      dim3(256),  0, stream, x, Wt, att_s, att_d, hbuf, asrc, adst);
  hipLaunchKernelGGL(k_mden,  dim3(1280),      dim3(256),  0, stream, asrc, adst, rowst, csr, m_, den_);
  hipLaunchKernelGGL(k_alpha, dim3(288, 10),   dim3(256),  0, stream, asrc, adst, csr, csrd, m_, den_, alphaC);
  hipLaunchKernelGGL(k_agg,   dim3(20480),     dim3(256),  0, stream, hbuf, alphaC, rowst, csr, gbias, spat);
  hipLaunchKernelGGL(k_lstm,  dim3(256),       dim3(512),  0, stream, spat,
                     Wp_ih0, Wp_hh0, bih0, bhh0, Wp_ih1, Wp_hh1, bih1, bhh1, lng, lnb, out);
}

// Round 17
// 367.469 us; speedup vs baseline: 1.1123x; 1.1123x over previous
//
#include <hip/hip_runtime.h>

#define T_ 10
#define B_ 4
#define N_ 2048
#define NTOT 8192
#define F_ 64
#define H_ 128
#define NHEADS 4
#define D_ 32
#define E_ 65536
#define EF 73728          // E + NTOT self-loops
#define HPAD 136

typedef __bf16 bf16x8 __attribute__((ext_vector_type(8)));
typedef float f32x4 __attribute__((ext_vector_type(4)));
typedef unsigned short u16;

__device__ __forceinline__ float bf2f(u16 u){
  union { unsigned int i; float f; } v; v.i = ((unsigned int)u) << 16; return v.f;
}
__device__ __forceinline__ u16 f2bf(float f){
  union { float f; unsigned int i; } v; v.f = f;
  return (u16)((v.i + 0x7FFFu + ((v.i >> 16) & 1u)) >> 16);
}
__device__ __forceinline__ float sigf(float x){ return 1.f / (1.f + __expf(-x)); }
__device__ __forceinline__ float tanhfast(float x){ return 1.f - 2.f / (__expf(2.f * x) + 1.f); }
__device__ __forceinline__ float lrelu(float x){ return x > 0.f ? x : 0.2f * x; }

// ---------------- CSR build ----------------
__global__ __launch_bounds__(256) void k_init(int* __restrict__ cnt){
  int i = blockIdx.x * 256 + threadIdx.x;
  if(i < NTOT) cnt[i] = 0;
}

__global__ __launch_bounds__(256) void k_count(const int* __restrict__ ei, int* __restrict__ cnt){
  int e = blockIdx.x * 256 + threadIdx.x;
  if(e < E_) atomicAdd(&cnt[ei[E_ + e]], 1);
}

__global__ __launch_bounds__(1024) void k_scan(const int* __restrict__ cnt,
                                               int* __restrict__ rowst,
                                               int* __restrict__ cursor){
  __shared__ int lds[1024];
  const int t = threadIdx.x;
  int loc[8];
  int s = 0;
  #pragma unroll
  for(int i = 0; i < 8; i++){ loc[i] = s; s += cnt[t * 8 + i]; }
  lds[t] = s;
  __syncthreads();
  for(int off = 1; off < 1024; off <<= 1){
    int v = lds[t];
    int a = (t >= off) ? lds[t - off] : 0;
    __syncthreads();
    lds[t] = v + a;
    __syncthreads();
  }
  const int base = (t > 0) ? lds[t - 1] : 0;
  #pragma unroll
  for(int i = 0; i < 8; i++){
    rowst[t * 8 + i] = base + loc[i];
    cursor[t * 8 + i] = 0;
  }
  if(t == 1023) rowst[NTOT] = lds[1023];
}

__global__ __launch_bounds__(256) void k_fill(const int* __restrict__ ei,
                                              const int* __restrict__ rowst,
                                              int* __restrict__ cursor,
                                              int* __restrict__ csr,
                                              int* __restrict__ csr_dst){
  int e = blockIdx.x * 256 + threadIdx.x;
  if(e < E_){
    int d = ei[E_ + e];
    int pos = atomicAdd(&cursor[d], 1);
    csr[rowst[d] + pos] = ei[e];
    csr_dst[rowst[d] + pos] = d;
  }
}

// ---- weight conversions: y=0..3 gate-permuted LSTM mats; y=4 GAT W^T ----
__global__ __launch_bounds__(256) void k_wconv(const float* __restrict__ s0, u16* __restrict__ d0,
                                               const float* __restrict__ s1, u16* __restrict__ d1,
                                               const float* __restrict__ s2, u16* __restrict__ d2,
                                               const float* __restrict__ s3, u16* __restrict__ d3,
                                               const float* __restrict__ W, u16* __restrict__ Wt){
  int i = blockIdx.x * 256 + threadIdx.x;
  if(blockIdx.y == 4){
    if(i < H_ * F_){
      int nn = i >> 6, f = i & 63;
      Wt[i] = f2bf(W[f * H_ + nn]);
    }
    return;
  }
  const float* src = blockIdx.y == 0 ? s0 : blockIdx.y == 1 ? s1 : blockIdx.y == 2 ? s2 : s3;
  u16* dst = blockIdx.y == 0 ? d0 : blockIdx.y == 1 ? d1 : blockIdx.y == 2 ? d2 : d3;
  if(i < 512 * 128){
    int p = i >> 7, k = i & 127;
    int w = p >> 6, g = (p >> 4) & 3, l = p & 15;
    int row = g * 128 + w * 16 + l;
    dst[i] = f2bf(src[row * 128 + k]);
  }
}

// ---------------- MFMA GAT projection + attention coefficients ----------------
__global__ __launch_bounds__(256) void k_projm(const float* __restrict__ x,
    const u16* __restrict__ Wt, const float* __restrict__ att_s, const float* __restrict__ att_d,
    u16* __restrict__ hbuf, float* __restrict__ asrc, float* __restrict__ adst){
  const int tid  = threadIdx.x;
  const int wave = tid >> 6;
  const int lane = tid & 63;
  const int l15  = lane & 15;
  const int quad = lane >> 4;
  const int r0   = blockIdx.x * 64 + wave * 16;
  const int row  = r0 + l15;
  const int t = row >> 13, nt = row & 8191;
  const int b = nt >> 11, n = nt & 2047;
  const float* xrow = x + (((size_t)b * T_ + t) * N_ + n) * F_;

  bf16x8 a[2];
  #pragma unroll
  for(int ks = 0; ks < 2; ks++){
    const float4 f0 = *(const float4*)(xrow + ks * 32 + quad * 8);
    const float4 f1 = *(const float4*)(xrow + ks * 32 + quad * 8 + 4);
    bf16x8 av;
    av[0] = (__bf16)f0.x; av[1] = (__bf16)f0.y; av[2] = (__bf16)f0.z; av[3] = (__bf16)f0.w;
    av[4] = (__bf16)f1.x; av[5] = (__bf16)f1.y; av[6] = (__bf16)f1.z; av[7] = (__bf16)f1.w;
    a[ks] = av;
  }

  f32x4 acc[8];
  #pragma unroll
  for(int c = 0; c < 8; c++){ f32x4 z = {0.f,0.f,0.f,0.f}; acc[c] = z; }
  #pragma unroll
  for(int c = 0; c < 8; c++){
    #pragma unroll
    for(int ks = 0; ks < 2; ks++){
      const bf16x8 bv = *(const bf16x8*)(Wt + (c * 16 + l15) * F_ + ks * 32 + quad * 8);
      acc[c] = __builtin_amdgcn_mfma_f32_16x16x32_bf16(a[ks], bv, acc[c], 0, 0, 0);
    }
  }

  float ps[4][4], pd[4][4];   // [r][head]
  #pragma unroll
  for(int r = 0; r < 4; r++)
    #pragma unroll
    for(int h = 0; h < 4; h++){ ps[r][h] = 0.f; pd[r][h] = 0.f; }

  #pragma unroll
  for(int c = 0; c < 8; c++){
    const int col = c * 16 + l15;
    const float asv = att_s[col];
    const float adv = att_d[col];
    const int head = c >> 1;
    #pragma unroll
    for(int r = 0; r < 4; r++){
      const float v = acc[c][r];
      hbuf[(size_t)(r0 + quad * 4 + r) * H_ + col] = f2bf(v);
      ps[r][head] += v * asv;
      pd[r][head] += v * adv;
    }
  }
  #pragma unroll
  for(int m = 8; m >= 1; m >>= 1){
    #pragma unroll
    for(int r = 0; r < 4; r++)
      #pragma unroll
      for(int h = 0; h < 4; h++){
        ps[r][h] += __shfl_xor(ps[r][h], m);
        pd[r][h] += __shfl_xor(pd[r][h], m);
      }
  }
  if(l15 == 0){
    #pragma unroll
    for(int r = 0; r < 4; r++){
      const int rw = r0 + quad * 4 + r;
      #pragma unroll
      for(int h = 0; h < 4; h++){
        asrc[(size_t)rw * NHEADS + h] = ps[r][h];
        adst[(size_t)rw * NHEADS + h] = pd[r][h];
      }
    }
  }
}

// ---------------- GAT P1: per-(t,node,head) softmax max+denominator ----------------
__global__ __launch_bounds__(256) void k_mden(const float* __restrict__ asrc,
    const float* __restrict__ adst, const int* __restrict__ rowst, const int* __restrict__ csr,
    float* __restrict__ m_, float* __restrict__ den_){
  const int gid = blockIdx.x * 256 + threadIdx.x;   // (t,node,head), head fastest
  const int head = gid & 3;
  const int node = (gid >> 2) & 8191;
  const int t = gid >> 15;
  const int rbase = t * NTOT;
  const float ad = adst[(size_t)(rbase + node) * NHEADS + head];
  float m = lrelu(asrc[(size_t)(rbase + node) * NHEADS + head] + ad);  // self-loop
  float den = 1.f;
  const int rs = rowst[node], re = rowst[node + 1];
  for(int i = rs; i < re; i++){
    const int s = csr[i];
    const float ev = lrelu(asrc[(size_t)(rbase + s) * NHEADS + head] + ad);
    const float nm = fmaxf(m, ev);
    den = den * __expf(m - nm) + __expf(ev - nm);
    m = nm;
  }
  m_[gid] = m;
  den_[gid] = den;
}

// ---------------- GAT P2: per-(t,csrpos) alpha for all 4 heads ----------------
__global__ __launch_bounds__(256) void k_alpha(const float* __restrict__ asrc,
    const float* __restrict__ adst, const int* __restrict__ csr, const int* __restrict__ csr_dst,
    const float* __restrict__ m_, const float* __restrict__ den_, float* __restrict__ alphaC){
  const int p = blockIdx.x * 256 + threadIdx.x;   // 0..EF-1
  const int t = blockIdx.y;
  const int rbase = t * NTOT;
  int s, d;
  if(p < E_){ s = csr[p]; d = csr_dst[p]; } else { s = d = p - E_; }
  const float4 as4 = *(const float4*)&asrc[(size_t)(rbase + s) * NHEADS];
  const float4 ad4 = *(const float4*)&adst[(size_t)(rbase + d) * NHEADS];
  const float4 m4  = *(const float4*)&m_[(size_t)(rbase + d) * NHEADS];
  const float4 dn4 = *(const float4*)&den_[(size_t)(rbase + d) * NHEADS];
  float4 o;
  o.x = __expf(lrelu(as4.x + ad4.x) - m4.x) / dn4.x;
  o.y = __expf(lrelu(as4.y + ad4.y) - m4.y) / dn4.y;
  o.z = __expf(lrelu(as4.z + ad4.z) - m4.z) / dn4.z;
  o.w = __expf(lrelu(as4.w + ad4.w) - m4.w) / dn4.w;
  *(float4*)&alphaC[((size_t)t * EF + p) * NHEADS] = o;
}

// ---------------- GAT P3: aggregation; wave per (t,node), lane covers dims (lane, lane+64) ----------------
__global__ __launch_bounds__(256) void k_agg(const u16* __restrict__ hbuf,
    const float* __restrict__ alphaC, const int* __restrict__ rowst, const int* __restrict__ csr,
    const float* __restrict__ gbias, u16* __restrict__ spat){
  const int tid = threadIdx.x;
  const int wave = tid >> 6;
  const int lane = tid & 63;
  const int task = blockIdx.x * 4 + wave;
  const int node = task & 8191;
  const int t = task >> 13;
  const int rbase = t * NTOT;
  const int d0 = lane, d1 = lane + 64;

  const float4 aself = *(const float4*)&alphaC[((size_t)t * EF + E_ + node) * NHEADS];
  float acc0 = (lane < 32 ? aself.x : aself.y) * bf2f(hbuf[(size_t)(rbase + node) * H_ + d0]);
  float acc1 = (lane < 32 ? aself.z : aself.w) * bf2f(hbuf[(size_t)(rbase + node) * H_ + d1]);
  const int rs = rowst[node], re = rowst[node + 1];
  for(int i = rs; i < re; i++){
    const int s = csr[i];
    const float4 av = *(const float4*)&alphaC[((size_t)t * EF + i) * NHEADS];
    const float a0 = lane < 32 ? av.x : av.y;
    const float a1 = lane < 32 ? av.z : av.w;
    acc0 += a0 * bf2f(hbuf[(size_t)(rbase + s) * H_ + d0]);
    acc1 += a1 * bf2f(hbuf[(size_t)(rbase + s) * H_ + d1]);
  }
  const float v0 = acc0 + gbias[d0];
  const float v1 = acc1 + gbias[d1];
  spat[(size_t)(rbase + node) * H_ + d0] = f2bf(v0 > 0.f ? v0 : 0.f);
  spat[(size_t)(rbase + node) * H_ + d1] = f2bf(v1 > 0.f ? v1 : 0.f);
}

// ---------------- 2-layer LSTM: R14 two-bank register pipeline, fragment-ordered LDS ------
// Compiler-scheduled (no explicit waitcnt). Lane L gathers exactly the 16B its B-fragment
// read wants; ds_write at nt*1024 + L*16 (lane-linear, conflict-free) and ds_read at
// nt*1024 + lane*16 (conflict-free). Fused LayerNorm epilogue writes `out` directly.
__global__ __launch_bounds__(512) __attribute__((amdgpu_waves_per_eu(2))) void k_lstm(
    const u16* __restrict__ spat,
    const u16* __restrict__ Wp_ih0, const u16* __restrict__ Wp_hh0,
    const float* __restrict__ bih0, const float* __restrict__ bhh0,
    const u16* __restrict__ Wp_ih1, const u16* __restrict__ Wp_hh1,
    const float* __restrict__ bih1, const float* __restrict__ bhh1,
    const float* __restrict__ lng, const float* __restrict__ lnb,
    float* __restrict__ out)
{
  __shared__ __align__(16) unsigned char wbuf[8][2][4096];   // 64 KB, fragment-ordered
  __shared__ __align__(16) u16 xin[32 * HPAD];               // 8.5 KB
  __shared__ __align__(16) u16 h0s[2][32 * HPAD];            // 17 KB
  __shared__ __align__(16) u16 h1s[2][32 * HPAD];            // 17 KB
  __shared__ __align__(16) float hfin[32 * 129];             // 16.5 KB fp32 final h1

  const int tid  = threadIdx.x;
  const int wave = tid >> 6;
  const int lane = tid & 63;
  const int l15  = lane & 15;
  const int quad = lane >> 4;
  const int n0   = blockIdx.x * 32;
  const int dim  = wave * 16 + l15;

  for(int i = tid; i < 2 * 32 * HPAD; i += 512){
    ((u16*)h0s)[i] = 0; ((u16*)h1s)[i] = 0;
  }
  // xin(t=0): 32 rows x 16 chunks of 16B = 512 chunks = one pass of 512 threads
  {
    const u16* src = spat + (size_t)n0 * H_;
    const int r = tid >> 4, c = tid & 15;
    *(uint4*)(xin + r * HPAD + c * 8) = *(const uint4*)(src + r * 128 + c * 8);
  }
  float cst[16];
  #pragma unroll
  for(int i = 0; i < 16; i++) cst[i] = 0.f;

  float bias[2][4];
  #pragma unroll
  for(int g = 0; g < 4; g++){
    bias[0][g] = bih0[g * 128 + dim] + bhh0[g * 128 + dim];
    bias[1][g] = bih1[g * 128 + dim] + bhh1[g * 128 + dim];
  }
  __syncthreads();

  unsigned char* wbuf_w = &wbuf[wave][0][0];
  // lane's gather base: chunk j of slice ks lives at M + loff + j*2048 + ks*32
  // (row = wave*64 + j*16 + l15, bytes quad*16 of the 64B k-slice)
  const size_t loff = (size_t)(wave * 64 + l15) * 128 + quad * 8;
  uint4 sA0, sB0, sC0, sD0, sA1, sB1, sC1, sD1;   // two staging banks (chunk j = A..D)

  #pragma unroll 1
  for(int t = 0; t < T_; t++){
    const int rp = t & 1, wp = rp ^ 1;
    #pragma unroll
    for(int layer = 0; layer < 2; layer++){
      const u16* Wih = layer ? Wp_ih1 : Wp_ih0;
      const u16* Whh = layer ? Wp_hh1 : Wp_hh0;
      const u16* xp  = layer ? h0s[wp] : xin;      // a-input, phases 0-3
      const u16* hp  = layer ? h1s[rp] : h0s[rp];  // a-input, phases 4-7

      f32x4 acc[2][4];
      #pragma unroll
      for(int nt = 0; nt < 4; nt++){
        const float bv = bias[layer][nt];
        f32x4 b4 = {bv, bv, bv, bv};
        acc[0][nt] = b4; acc[1][nt] = b4;
      }

      // prologue: L(s0->bank0); W(bank0->buf0); L(s1->bank1); L(s2->bank0)
      {
        const u16* g0 = Wih + loff;
        sA0 = *(const uint4*)(g0);        sB0 = *(const uint4*)(g0 + 2048);
        sC0 = *(const uint4*)(g0 + 4096); sD0 = *(const uint4*)(g0 + 6144);
        unsigned char* wd = wbuf_w + lane * 16;
        *(uint4*)(wd) = sA0;        *(uint4*)(wd + 1024) = sB0;
        *(uint4*)(wd + 2048) = sC0; *(uint4*)(wd + 3072) = sD0;
        const u16* g1 = Wih + loff + 32;
        sA1 = *(const uint4*)(g1);        sB1 = *(const uint4*)(g1 + 2048);
        sC1 = *(const uint4*)(g1 + 4096); sD1 = *(const uint4*)(g1 + 6144);
        const u16* g2 = Wih + loff + 64;
        sA0 = *(const uint4*)(g2);        sB0 = *(const uint4*)(g2 + 2048);
        sC0 = *(const uint4*)(g2 + 4096); sD0 = *(const uint4*)(g2 + 6144);
      }

      #pragma unroll 1
      for(int pp = 0; pp < 4; pp++){
        const int p0 = pp * 2;
        // even phase p0: write bank1->buf1; load slice p0+3 -> bank1; compute p0 from buf0
        {
          unsigned char* wd = wbuf_w + 4096 + lane * 16;
          *(uint4*)(wd) = sA1;        *(uint4*)(wd + 1024) = sB1;
          *(uint4*)(wd + 2048) = sC1; *(uint4*)(wd + 3072) = sD1;
          if(p0 < 5){
            const int q = p0 + 3;
            const u16* g = ((q < 4) ? Wih : Whh) + loff + (q & 3) * 32;
            sA1 = *(const uint4*)(g);        sB1 = *(const uint4*)(g + 2048);
            sC1 = *(const uint4*)(g + 4096); sD1 = *(const uint4*)(g + 6144);
          }
          const u16* ap = (p0 < 4) ? xp : hp;
          const int ka = (p0 & 3) * 32 + quad * 8;
          const bf16x8 a0 = *(const bf16x8*)(ap + l15 * HPAD + ka);
          const bf16x8 a1 = *(const bf16x8*)(ap + (16 + l15) * HPAD + ka);
          const unsigned char* rb = wbuf_w;
          #pragma unroll
          for(int nt = 0; nt < 4; nt++){
            const bf16x8 b = *(const bf16x8*)(rb + nt * 1024 + lane * 16);
            acc[0][nt] = __builtin_amdgcn_mfma_f32_16x16x32_bf16(a0, b, acc[0][nt], 0, 0, 0);
            acc[1][nt] = __builtin_amdgcn_mfma_f32_16x16x32_bf16(a1, b, acc[1][nt], 0, 0, 0);
          }
        }
        const int p1 = p0 + 1;
        // odd phase p1: write bank0->buf0 if p1<7; load slice p1+3 -> bank0 if p1<5; compute p1 from buf1
        {
          if(p1 < 7){
            unsigned char* wd = wbuf_w + lane * 16;
            *(uint4*)(wd) = sA0;        *(uint4*)(wd + 1024) = sB0;
            *(uint4*)(wd + 2048) = sC0; *(uint4*)(wd + 3072) = sD0;
          }
          if(p1 < 5){
            const int q = p1 + 3;   // 4 or 6 -> Whh
            const u16* g = Whh + loff + (q & 3) * 32;
            sA0 = *(const uint4*)(g);        sB0 = *(const uint4*)(g + 2048);
            sC0 = *(const uint4*)(g + 4096); sD0 = *(const uint4*)(g + 6144);
          }
          const u16* ap = (p1 < 4) ? xp : hp;
          const int ka = (p1 & 3) * 32 + quad * 8;
          const bf16x8 a0 = *(const bf16x8*)(ap + l15 * HPAD + ka);
          const bf16x8 a1 = *(const bf16x8*)(ap + (16 + l15) * HPAD + ka);
          const unsigned char* rb = wbuf_w + 4096;
          #pragma unroll
          for(int nt = 0; nt < 4; nt++){
            const bf16x8 b = *(const bf16x8*)(rb + nt * 1024 + lane * 16);
            acc[0][nt] = __builtin_amdgcn_mfma_f32_16x16x32_bf16(a0, b, acc[0][nt], 0, 0, 0);
            acc[1][nt] = __builtin_amdgcn_mfma_f32_16x16x32_bf16(a1, b, acc[1][nt], 0, 0, 0);
          }
        }
      }

      // in-register epilogue: C/D row = quad*4 + r (node), this lane's dim fixed
      u16* hcur = layer ? h1s[wp] : h0s[wp];
      #pragma unroll
      for(int mt = 0; mt < 2; mt++){
        #pragma unroll
        for(int r = 0; r < 4; r++){
          const int node = mt * 16 + quad * 4 + r;
          const float gi = acc[mt][0][r];
          const float gf = acc[mt][1][r];
          const float gg = acc[mt][2][r];
          const float go = acc[mt][3][r];
          const int ci = layer * 8 + mt * 4 + r;
          const float c = sigf(gf) * cst[ci] + sigf(gi) * tanhfast(gg);
          cst[ci] = c;
          const float hv = sigf(go) * tanhfast(c);
          hcur[node * HPAD + dim] = f2bf(hv);
          if(layer == 1 && t == T_ - 1)
            hfin[node * 129 + dim] = hv;
        }
      }
      // after layer 1: copy next timestep's x-tile (barrier below covers it)
      if(layer == 1 && t < T_ - 1){
        const u16* src = spat + (size_t)((t + 1) * NTOT + n0) * H_;
        const int r = tid >> 4, c = tid & 15;
        *(uint4*)(xin + r * HPAD + c * 8) = *(const uint4*)(src + r * 128 + c * 8);
      }
      __syncthreads();
    }
  }

  // ---- fused LayerNorm: 16 threads per node, 8 dims each, fp32 from hfin ----
  {
    const int node = tid >> 4;
    const int c0 = (tid & 15) * 8;
    float v[8];
    #pragma unroll
    for(int j = 0; j < 8; j++) v[j] = hfin[node * 129 + c0 + j];
    float s = 0.f;
    #pragma unroll
    for(int j = 0; j < 8; j++) s += v[j];
    #pragma unroll
    for(int m = 8; m >= 1; m >>= 1) s += __shfl_xor(s, m);
    const float mu = s * (1.f / H_);
    float q = 0.f;
    #pragma unroll
    for(int j = 0; j < 8; j++){ const float d = v[j] - mu; q += d * d; }
    #pragma unroll
    for(int m = 8; m >= 1; m >>= 1) q += __shfl_xor(q, m);
    const float rstd = rsqrtf(q * (1.f / H_) + 1e-5f);
    #pragma unroll
    for(int j = 0; j < 8; j++)
      out[(size_t)(n0 + node) * H_ + c0 + j] = (v[j] - mu) * rstd * lng[c0 + j] + lnb[c0 + j];
  }
}

extern "C" void kernel_launch(void* const* d_in, const int* in_sizes, int n_in,
                              void* d_out, int out_size, void* d_ws, size_t ws_size,
                              hipStream_t stream) {
  (void)in_sizes; (void)n_in; (void)out_size; (void)ws_size;
  const float* x     = (const float*)d_in[0];
  const float* W     = (const float*)d_in[1];
  const float* att_s = (const float*)d_in[2];
  const float* att_d = (const float*)d_in[3];
  const float* gbias = (const float*)d_in[4];
  const float* Wih0  = (const float*)d_in[5];
  const float* Whh0  = (const float*)d_in[6];
  const float* bih0  = (const float*)d_in[7];
  const float* bhh0  = (const float*)d_in[8];
  const float* Wih1  = (const float*)d_in[9];
  const float* Whh1  = (const float*)d_in[10];
  const float* bih1  = (const float*)d_in[11];
  const float* bhh1  = (const float*)d_in[12];
  const float* lng   = (const float*)d_in[13];
  const float* lnb   = (const float*)d_in[14];
  const int*   ei    = (const int*)d_in[15];
  float* out = (float*)d_out;

  char* p = (char*)d_ws;
  auto carve = [&](size_t bytes) -> void* {
    void* r = (void*)p;
    p += (bytes + 255) & ~(size_t)255;
    return r;
  };
  u16* Wp_ih0 = (u16*)carve(512 * 128 * 2);
  u16* Wp_hh0 = (u16*)carve(512 * 128 * 2);
  u16* Wp_ih1 = (u16*)carve(512 * 128 * 2);
  u16* Wp_hh1 = (u16*)carve(512 * 128 * 2);
  u16* Wt     = (u16*)carve(H_ * F_ * 2);
  u16*   hbuf   = (u16*)carve((size_t)T_ * NTOT * H_ * 2);           // 21 MB bf16
  float* asrc   = (float*)carve((size_t)T_ * NTOT * NHEADS * 4);
  float* adst   = (float*)carve((size_t)T_ * NTOT * NHEADS * 4);
  float* m_     = (float*)carve((size_t)T_ * NTOT * NHEADS * 4);
  float* den_   = (float*)carve((size_t)T_ * NTOT * NHEADS * 4);
  float* alphaC = (float*)carve((size_t)T_ * EF * NHEADS * 4);       // 11.8 MB
  u16*   spat   = (u16*)carve((size_t)T_ * NTOT * H_ * 2);           // 21 MB bf16
  int*   cnt    = (int*)carve(NTOT * 4);
  int*   curs   = (int*)carve(NTOT * 4);
  int*   rowst  = (int*)carve((NTOT + 1) * 4);
  int*   csr    = (int*)carve((size_t)E_ * 4);
  int*   csrd   = (int*)carve((size_t)E_ * 4);

  hipLaunchKernelGGL(k_init,  dim3(32),        dim3(256),  0, stream, cnt);
  hipLaunchKernelGGL(k_count, dim3(256),       dim3(256),  0, stream, ei, cnt);
  hipLaunchKernelGGL(k_scan,  dim3(1),         dim3(1024), 0, stream, cnt, rowst, curs);
  hipLaunchKernelGGL(k_fill,  dim3(256),       dim3(256),  0, stream, ei, rowst, curs, csr, csrd);
  hipLaunchKernelGGL(k_wconv, dim3(256, 5),    dim3(256),  0, stream,
                     Wih0, Wp_ih0, Whh0, Wp_hh0, Wih1, Wp_ih1, Whh1, Wp_hh1, W, Wt);
  hipLaunchKernelGGL(k_projm, dim3(1280),      dim3(256),  0, stream, x, Wt, att_s, att_d, hbuf, asrc, adst);
  hipLaunchKernelGGL(k_mden,  dim3(1280),      dim3(256),  0, stream, asrc, adst, rowst, csr, m_, den_);
  hipLaunchKernelGGL(k_alpha, dim3(288, 10),   dim3(256),  0, stream, asrc, adst, csr, csrd, m_, den_, alphaC);
  hipLaunchKernelGGL(k_agg,   dim3(20480),     dim3(256),  0, stream, hbuf, alphaC, rowst, csr, gbias, spat);
  hipLaunchKernelGGL(k_lstm,  dim3(256),       dim3(512),  0, stream, spat,
                     Wp_ih0, Wp_hh0, bih0, bhh0, Wp_ih1, Wp_hh1, bih1, bhh1, lng, lnb, out);
}